// Round 1
// baseline (1739.883 us; speedup 1.0000x reference)
//
#include <hip/hip_runtime.h>
#include <math.h>

#define HIDDEN 768
#define KEY    128
#define INTER  1536
#define NB     4
#define SEQ    2048
#define MTOT   (NB*SEQ)          // 8192
#define ETOT   (2*INTER+KEY)     // 3200

// ---- bf16 bit helpers (avoid hip_bf16 API surface; round-to-nearest-even) ----
__device__ __forceinline__ unsigned short f2bfbits(float x) {
    union { float f; unsigned int u; } a; a.f = x;
    unsigned int r = a.u + 0x7fffu + ((a.u >> 16) & 1u);
    return (unsigned short)(r >> 16);
}
__device__ __forceinline__ float bfbits2f(unsigned short b) {
    union { float f; unsigned int u; } a; a.u = ((unsigned int)b) << 16;
    return a.f;
}

// ---- K0: per-batch softmax length scale ----
__global__ __launch_bounds__(256) void scale_kernel(const int* __restrict__ mask,
                                                    float* __restrict__ scaleb) {
    __shared__ int red[256];
    int b = blockIdx.x;
    int s = 0;
    for (int j = threadIdx.x; j < SEQ; j += 256)
        s += (mask[b*SEQ + j] != 0) ? 1 : 0;
    red[threadIdx.x] = s;
    __syncthreads();
    for (int step = 128; step > 0; step >>= 1) {
        if (threadIdx.x < step) red[threadIdx.x] += red[threadIdx.x + step];
        __syncthreads();
    }
    if (threadIdx.x == 0) {
        float l = fmaxf((float)red[0], 1.0f);
        scaleb[b] = logf(l) / logf(512.0f);
    }
}

// ---- K1: h = silu(X@Wi + bi); split into u, v, q, k (gamma/beta applied) ----
__global__ __launch_bounds__(256) void gemm1_kernel(
    const float* __restrict__ X, const float* __restrict__ Wi,
    const float* __restrict__ bi, const float* __restrict__ gamma,
    const float* __restrict__ beta,
    float* __restrict__ u, float* __restrict__ v,
    float* __restrict__ qb, float* __restrict__ kb)
{
    __shared__ float As[16][68];
    __shared__ float Bs[16][68];
    const int tid = threadIdx.x;
    const int tx = tid & 15, ty = tid >> 4;
    const int row0 = blockIdx.y * 64;
    const int col0 = blockIdx.x * 64;
    float acc[4][4] = {};
    for (int k0 = 0; k0 < HIDDEN; k0 += 16) {
        #pragma unroll
        for (int e = 0; e < 4; e++) {
            int p = tid + e*256;
            int r = p >> 4, kc = p & 15;
            As[kc][r] = X[(size_t)(row0 + r)*HIDDEN + k0 + kc];
        }
        #pragma unroll
        for (int e = 0; e < 4; e++) {
            int p = tid + e*256;
            int kc = p >> 6, c = p & 63;
            Bs[kc][c] = Wi[(size_t)(k0 + kc)*ETOT + col0 + c];
        }
        __syncthreads();
        #pragma unroll
        for (int kk = 0; kk < 16; kk++) {
            float4 a = *(const float4*)&As[kk][ty*4];
            float4 b = *(const float4*)&Bs[kk][tx*4];
            float av[4] = {a.x, a.y, a.z, a.w};
            float bv[4] = {b.x, b.y, b.z, b.w};
            #pragma unroll
            for (int i = 0; i < 4; i++)
                #pragma unroll
                for (int j = 0; j < 4; j++)
                    acc[i][j] += av[i] * bv[j];
        }
        __syncthreads();
    }
    #pragma unroll
    for (int i = 0; i < 4; i++) {
        int m = row0 + ty*4 + i;
        #pragma unroll
        for (int j = 0; j < 4; j++) {
            int n = col0 + tx*4 + j;
            float x = acc[i][j] + bi[n];
            float h = x / (1.0f + __expf(-x));   // silu
            if (n < INTER) {
                u[(size_t)m*INTER + n] = h;
            } else if (n < 2*INTER) {
                v[(size_t)m*INTER + (n - INTER)] = h;
            } else {
                int c = n - 2*INTER;
                qb[(size_t)m*KEY + c] = h*gamma[c]       + beta[c];
                kb[(size_t)m*KEY + c] = h*gamma[KEY + c] + beta[KEY + c];
            }
        }
    }
}

// ---- K2: unnormalized attention probs P (bf16) + row sums l ----
// No max-subtraction: |scores| is tiny (<~3) before masking, so exp never
// overflows; masked entries are exactly 0. 4 rows per block.
__global__ __launch_bounds__(256) void attn_p_kernel(
    const float* __restrict__ qb, const float* __restrict__ kb,
    const int* __restrict__ mask, const float* __restrict__ scaleb,
    unsigned short* __restrict__ P, float* __restrict__ lbuf)
{
    __shared__ __align__(16) float qs4[KEY][4];   // qs4[c][r]
    __shared__ unsigned short ks[256][132];       // chunk of 256 k-rows, bf16, padded
    __shared__ float red[4][4];
    const int tid = threadIdx.x;
    const int i0 = blockIdx.x * 4;        // global row (b*SEQ + s)
    const int b = i0 / SEQ;
    const float scale = scaleb[b] * 0.08838834764831845f; // * 1/sqrt(128)

    if (tid < KEY) {
        #pragma unroll
        for (int r = 0; r < 4; r++)
            qs4[tid][r] = qb[(size_t)(i0 + r)*KEY + tid];
    }
    float lacc[4] = {0.f, 0.f, 0.f, 0.f};

    for (int j0 = 0; j0 < SEQ; j0 += 256) {
        __syncthreads();  // previous chunk fully consumed
        #pragma unroll
        for (int e = 0; e < 32; e++) {
            int p4 = tid + e*256;                  // float4 index in 256x128 chunk
            int rr = p4 >> 5, c4 = (p4 & 31) * 4;
            float4 kv = *(const float4*)&kb[(size_t)(b*SEQ + j0 + rr)*KEY + c4];
            ushort4 pk;
            pk.x = f2bfbits(kv.x); pk.y = f2bfbits(kv.y);
            pk.z = f2bfbits(kv.z); pk.w = f2bfbits(kv.w);
            *(ushort4*)&ks[rr][c4] = pk;
        }
        __syncthreads();
        float s[4] = {0.f, 0.f, 0.f, 0.f};
        #pragma unroll 8
        for (int c = 0; c < KEY; c++) {
            float kv = bfbits2f(ks[tid][c]);
            float4 qv = *(const float4*)&qs4[c][0];
            s[0] += qv.x * kv; s[1] += qv.y * kv;
            s[2] += qv.z * kv; s[3] += qv.w * kv;
        }
        int j = j0 + tid;
        bool mk = (mask[b*SEQ + j] != 0);
        #pragma unroll
        for (int r = 0; r < 4; r++) {
            float p = mk ? __expf(s[r] * scale) : 0.0f;
            P[(size_t)(i0 + r)*SEQ + j] = f2bfbits(p);
            lacc[r] += p;
        }
    }
    // block reduce lacc per row
    int lane = tid & 63, wave = tid >> 6;
    #pragma unroll
    for (int r = 0; r < 4; r++) {
        float x = lacc[r];
        #pragma unroll
        for (int off = 32; off > 0; off >>= 1)
            x += __shfl_down(x, off, 64);
        if (lane == 0) red[wave][r] = x;
    }
    __syncthreads();
    if (tid < 4)
        lbuf[i0 + tid] = red[0][tid] + red[1][tid] + red[2][tid] + red[3][tid];
}

// ---- K3: ctx = P@v per batch; epilogue g = u * ctx / l, written in-place to u ----
__global__ __launch_bounds__(256) void gemm_pv_kernel(
    const unsigned short* __restrict__ P, const float* __restrict__ v,
    const float* __restrict__ lbuf, float* __restrict__ u)
{
    __shared__ float As[16][68];
    __shared__ float Bs[16][68];
    const int tid = threadIdx.x;
    const int tx = tid & 15, ty = tid >> 4;
    const int z = blockIdx.z;
    const int row0 = blockIdx.y * 64;
    const int col0 = blockIdx.x * 64;
    const unsigned short* Pb = P + (size_t)z*SEQ*SEQ;
    const float* Bb = v + (size_t)z*SEQ*INTER;
    float acc[4][4] = {};
    for (int k0 = 0; k0 < SEQ; k0 += 16) {
        #pragma unroll
        for (int e = 0; e < 4; e++) {
            int p = tid + e*256;
            int r = p >> 4, kc = p & 15;
            As[kc][r] = bfbits2f(Pb[(size_t)(row0 + r)*SEQ + k0 + kc]);
        }
        #pragma unroll
        for (int e = 0; e < 4; e++) {
            int p = tid + e*256;
            int kc = p >> 6, c = p & 63;
            Bs[kc][c] = Bb[(size_t)(k0 + kc)*INTER + col0 + c];
        }
        __syncthreads();
        #pragma unroll
        for (int kk = 0; kk < 16; kk++) {
            float4 a = *(const float4*)&As[kk][ty*4];
            float4 b = *(const float4*)&Bs[kk][tx*4];
            float av[4] = {a.x, a.y, a.z, a.w};
            float bv[4] = {b.x, b.y, b.z, b.w};
            #pragma unroll
            for (int i = 0; i < 4; i++)
                #pragma unroll
                for (int j = 0; j < 4; j++)
                    acc[i][j] += av[i] * bv[j];
        }
        __syncthreads();
    }
    #pragma unroll
    for (int i = 0; i < 4; i++) {
        int m = z*SEQ + row0 + ty*4 + i;
        float linv = 1.0f / lbuf[m];
        #pragma unroll
        for (int j = 0; j < 4; j++) {
            int n = col0 + tx*4 + j;
            size_t idx = (size_t)m*INTER + n;
            u[idx] = u[idx] * (acc[i][j] * linv);
        }
    }
}

// ---- K4: out = g@Wo + bo ----
__global__ __launch_bounds__(256) void gemm2_kernel(
    const float* __restrict__ g, const float* __restrict__ Wo,
    const float* __restrict__ bo, float* __restrict__ out)
{
    __shared__ float As[16][68];
    __shared__ float Bs[16][68];
    const int tid = threadIdx.x;
    const int tx = tid & 15, ty = tid >> 4;
    const int row0 = blockIdx.y * 64;
    const int col0 = blockIdx.x * 64;
    float acc[4][4] = {};
    for (int k0 = 0; k0 < INTER; k0 += 16) {
        #pragma unroll
        for (int e = 0; e < 4; e++) {
            int p = tid + e*256;
            int r = p >> 4, kc = p & 15;
            As[kc][r] = g[(size_t)(row0 + r)*INTER + k0 + kc];
        }
        #pragma unroll
        for (int e = 0; e < 4; e++) {
            int p = tid + e*256;
            int kc = p >> 6, c = p & 63;
            Bs[kc][c] = Wo[(size_t)(k0 + kc)*HIDDEN + col0 + c];
        }
        __syncthreads();
        #pragma unroll
        for (int kk = 0; kk < 16; kk++) {
            float4 a = *(const float4*)&As[kk][ty*4];
            float4 b = *(const float4*)&Bs[kk][tx*4];
            float av[4] = {a.x, a.y, a.z, a.w};
            float bv[4] = {b.x, b.y, b.z, b.w};
            #pragma unroll
            for (int i = 0; i < 4; i++)
                #pragma unroll
                for (int j = 0; j < 4; j++)
                    acc[i][j] += av[i] * bv[j];
        }
        __syncthreads();
    }
    #pragma unroll
    for (int i = 0; i < 4; i++) {
        int m = row0 + ty*4 + i;
        #pragma unroll
        for (int j = 0; j < 4; j++) {
            int n = col0 + tx*4 + j;
            out[(size_t)m*HIDDEN + n] = acc[i][j] + bo[n];
        }
    }
}

extern "C" void kernel_launch(void* const* d_in, const int* in_sizes, int n_in,
                              void* d_out, int out_size, void* d_ws, size_t ws_size,
                              hipStream_t stream)
{
    const float* X     = (const float*)d_in[0];
    const int*   mask  = (const int*)d_in[1];
    // d_in[2] position_ids unused by the forward
    const float* Wi    = (const float*)d_in[3];
    const float* bi    = (const float*)d_in[4];
    const float* gamma = (const float*)d_in[5];
    const float* beta  = (const float*)d_in[6];
    const float* Wo    = (const float*)d_in[7];
    const float* bo    = (const float*)d_in[8];
    float* out = (float*)d_out;

    // workspace layout (fp32 unless noted): u, v, q, k, l, scale, P(bf16)
    float* u   = (float*)d_ws;                         // 8192*1536
    float* v   = u  + (size_t)MTOT*INTER;              // 8192*1536
    float* qb  = v  + (size_t)MTOT*INTER;              // 8192*128
    float* kb  = qb + (size_t)MTOT*KEY;                // 8192*128
    float* lb  = kb + (size_t)MTOT*KEY;                // 8192
    float* scb = lb + MTOT;                            // 4 (+pad)
    unsigned short* P = (unsigned short*)(scb + 8);    // 4*2048*2048 bf16

    scale_kernel<<<NB, 256, 0, stream>>>(mask, scb);
    gemm1_kernel<<<dim3(ETOT/64, MTOT/64), 256, 0, stream>>>(X, Wi, bi, gamma, beta, u, v, qb, kb);
    attn_p_kernel<<<MTOT/4, 256, 0, stream>>>(qb, kb, mask, scb, P, lb);
    gemm_pv_kernel<<<dim3(INTER/64, SEQ/64, NB), 256, 0, stream>>>(P, v, lb, u);
    gemm2_kernel<<<dim3(HIDDEN/64, MTOT/64), 256, 0, stream>>>(u, Wo, bo, out);
}

// Round 2
// 328.478 us; speedup vs baseline: 5.2968x; 5.2968x over previous
//
#include <hip/hip_runtime.h>
#include <math.h>

#define HIDDEN 768
#define KEY    128
#define INTER  1536
#define NB     4
#define SEQ    2048
#define MTOT   (NB*SEQ)          // 8192
#define ETOT   (2*INTER+KEY)     // 3200

typedef short bf16x8 __attribute__((ext_vector_type(8)));
typedef float f32x4  __attribute__((ext_vector_type(4)));

// ---- bf16 bit helpers (round-to-nearest-even) ----
__device__ __forceinline__ unsigned short f2bfbits(float x) {
    union { float f; unsigned int u; } a; a.f = x;
    unsigned int r = a.u + 0x7fffu + ((a.u >> 16) & 1u);
    return (unsigned short)(r >> 16);
}
__device__ __forceinline__ float bfbits2f(unsigned short b) {
    union { float f; unsigned int u; } a; a.u = ((unsigned int)b) << 16;
    return a.f;
}

// async global->LDS, 16 bytes per lane
__device__ __forceinline__ void gl2lds16(const unsigned short* g, unsigned short* l) {
    __builtin_amdgcn_global_load_lds(
        (const __attribute__((address_space(1))) unsigned int*)g,
        (__attribute__((address_space(3))) unsigned int*)l, 16, 0, 0);
}

// ---- K0: per-batch softmax length scale ----
__global__ __launch_bounds__(256) void scale_kernel(const int* __restrict__ mask,
                                                    float* __restrict__ scaleb) {
    __shared__ int red[256];
    int b = blockIdx.x;
    int s = 0;
    for (int j = threadIdx.x; j < SEQ; j += 256)
        s += (mask[b*SEQ + j] != 0) ? 1 : 0;
    red[threadIdx.x] = s;
    __syncthreads();
    for (int step = 128; step > 0; step >>= 1) {
        if (threadIdx.x < step) red[threadIdx.x] += red[threadIdx.x + step];
        __syncthreads();
    }
    if (threadIdx.x == 0) {
        float l = fmaxf((float)red[0], 1.0f);
        scaleb[b] = logf(l) / logf(512.0f);
    }
}

// ---- fp32 -> bf16 elementwise ----
__global__ __launch_bounds__(256) void cvt_bf16_kernel(const float* __restrict__ in,
                                                       unsigned short* __restrict__ out, int n4) {
    int i = blockIdx.x*256 + threadIdx.x;
    if (i < n4) {
        float4 v = ((const float4*)in)[i];
        ushort4 o;
        o.x = f2bfbits(v.x); o.y = f2bfbits(v.y);
        o.z = f2bfbits(v.z); o.w = f2bfbits(v.w);
        ((ushort4*)out)[i] = o;
    }
}

// ---- transpose fp32 [R][C] -> bf16 [C][R] ----
__global__ __launch_bounds__(256) void transpose_cvt(const float* __restrict__ in,
                                                     unsigned short* __restrict__ out,
                                                     int R, int C) {
    __shared__ unsigned short tile[32][33];
    int c0 = blockIdx.x*32, r0 = blockIdx.y*32;
    int tx = threadIdx.x & 31, ty4 = (threadIdx.x >> 5)*4;
    #pragma unroll
    for (int rr = 0; rr < 4; rr++) {
        int r = ty4 + rr;
        tile[r][tx] = f2bfbits(in[(size_t)(r0+r)*C + c0+tx]);
    }
    __syncthreads();
    #pragma unroll
    for (int rr = 0; rr < 4; rr++) {
        int r = ty4 + rr;
        out[(size_t)(c0+r)*R + r0+tx] = tile[tx][r];
    }
}

// ---- per-batch transpose v bf16 [b*SEQ+s][INTER] -> vT [b][INTER][SEQ] ----
__global__ __launch_bounds__(256) void transpose_v(const unsigned short* __restrict__ v,
                                                   unsigned short* __restrict__ vT) {
    __shared__ unsigned short tile[32][33];
    int z = blockIdx.z;
    int c0 = blockIdx.x*32, s0 = blockIdx.y*32;
    int tx = threadIdx.x & 31, ty4 = (threadIdx.x >> 5)*4;
    #pragma unroll
    for (int rr = 0; rr < 4; rr++) {
        int s = ty4 + rr;
        tile[s][tx] = v[(size_t)(z*SEQ + s0+s)*INTER + c0+tx];
    }
    __syncthreads();
    #pragma unroll
    for (int rr = 0; rr < 4; rr++) {
        int c = ty4 + rr;
        vT[((size_t)z*INTER + c0+c)*SEQ + s0+tx] = tile[tx][c];
    }
}

// ---- shared MFMA K-loop: 128x128 tile, BK=32, A and B^T both [row][K] bf16 ----
__device__ __forceinline__ void mfma_core(
    const unsigned short* __restrict__ Abase, int lda,
    const unsigned short* __restrict__ Bbase, int ldb,
    unsigned short* As, unsigned short* Bs,
    f32x4 acc[4][4], int tid, int ktot)
{
    const int lane = tid & 63, wave = tid >> 6;
    const int wm = (wave >> 1) << 6, wn = (wave & 1) << 6;
    const int lm = lane & 15;
    const int q8 = (lane >> 4) << 3;
    const int row_a = tid >> 2, col_a = (tid & 3) << 3;   // staging round 0
    const int row_b = row_a + 64;                          // staging round 1

    for (int k0 = 0; k0 < ktot; k0 += 32) {
        if (k0) __syncthreads();
        gl2lds16(Abase + (size_t)row_a*lda + k0 + col_a, As + tid*8);
        gl2lds16(Bbase + (size_t)row_a*ldb + k0 + col_a, Bs + tid*8);
        gl2lds16(Abase + (size_t)row_b*lda + k0 + col_a, As + (tid+256)*8);
        gl2lds16(Bbase + (size_t)row_b*ldb + k0 + col_a, Bs + (tid+256)*8);
        __syncthreads();   // compiler emits vmcnt(0) drain here
        bf16x8 af[4], bfr[4];
        #pragma unroll
        for (int i = 0; i < 4; i++)
            af[i] = *(const bf16x8*)&As[(wm + i*16 + lm)*32 + q8];
        #pragma unroll
        for (int j = 0; j < 4; j++)
            bfr[j] = *(const bf16x8*)&Bs[(wn + j*16 + lm)*32 + q8];
        #pragma unroll
        for (int i = 0; i < 4; i++)
            #pragma unroll
            for (int j = 0; j < 4; j++)
                acc[i][j] = __builtin_amdgcn_mfma_f32_16x16x32_bf16(af[i], bfr[j], acc[i][j], 0, 0, 0);
    }
}

#define EPILOG_IDX \
    const int lane = tid & 63, wave = tid >> 6; \
    const int wm = (wave >> 1) << 6, wn = (wave & 1) << 6; \
    const int cn = lane & 15, r4 = (lane >> 4) << 2;

// ---- K1: h = silu(X@Wi + bi); split u/v bf16, q/k bf16 ----
__global__ __launch_bounds__(256) void gemm1_mfma(
    const unsigned short* __restrict__ Xb, const unsigned short* __restrict__ WiT,
    const float* __restrict__ bi, const float* __restrict__ gamma, const float* __restrict__ beta,
    unsigned short* __restrict__ u, unsigned short* __restrict__ v,
    unsigned short* __restrict__ qb, unsigned short* __restrict__ kb)
{
    __shared__ __align__(16) unsigned short As[128*32];
    __shared__ __align__(16) unsigned short Bs[128*32];
    const int tid = threadIdx.x;
    const int row0 = blockIdx.y*128, col0 = blockIdx.x*128;
    f32x4 acc[4][4];
    #pragma unroll
    for (int i = 0; i < 4; i++)
        #pragma unroll
        for (int j = 0; j < 4; j++)
            acc[i][j] = (f32x4){0.f,0.f,0.f,0.f};
    mfma_core(Xb + (size_t)row0*HIDDEN, HIDDEN, WiT + (size_t)col0*HIDDEN, HIDDEN,
              As, Bs, acc, tid, HIDDEN);
    EPILOG_IDX
    #pragma unroll
    for (int j = 0; j < 4; j++) {
        int n = col0 + wn + j*16 + cn;
        float bin = bi[n];
        #pragma unroll
        for (int i = 0; i < 4; i++) {
            #pragma unroll
            for (int r = 0; r < 4; r++) {
                int m = row0 + wm + i*16 + r4 + r;
                float x = acc[i][j][r] + bin;
                float h = x / (1.0f + __expf(-x));
                if (col0 < INTER) {
                    u[(size_t)m*INTER + n] = f2bfbits(h);
                } else if (col0 < 2*INTER) {
                    v[(size_t)m*INTER + (n - INTER)] = f2bfbits(h);
                } else {
                    int c = n - 2*INTER;
                    qb[(size_t)m*KEY + c] = f2bfbits(h*gamma[c]       + beta[c]);
                    kb[(size_t)m*KEY + c] = f2bfbits(h*gamma[KEY + c] + beta[KEY + c]);
                }
            }
        }
    }
}

// ---- K2: P = exp(scale * q@k^T) masked, bf16, unnormalized ----
__global__ __launch_bounds__(256) void attn_mfma(
    const unsigned short* __restrict__ qb, const unsigned short* __restrict__ kb,
    const int* __restrict__ mask, const float* __restrict__ scaleb,
    unsigned short* __restrict__ P)
{
    __shared__ __align__(16) unsigned short As[128*32];
    __shared__ __align__(16) unsigned short Bs[128*32];
    const int tid = threadIdx.x;
    const int z = blockIdx.z;
    const int row0 = blockIdx.y*128, col0 = blockIdx.x*128;
    f32x4 acc[4][4];
    #pragma unroll
    for (int i = 0; i < 4; i++)
        #pragma unroll
        for (int j = 0; j < 4; j++)
            acc[i][j] = (f32x4){0.f,0.f,0.f,0.f};
    mfma_core(qb + ((size_t)z*SEQ + row0)*KEY, KEY, kb + ((size_t)z*SEQ + col0)*KEY, KEY,
              As, Bs, acc, tid, KEY);
    const float st = scaleb[z] * 0.08838834764831845f;  // 1/sqrt(128)
    EPILOG_IDX
    #pragma unroll
    for (int j = 0; j < 4; j++) {
        int n = col0 + wn + j*16 + cn;
        int mk = mask[z*SEQ + n];
        #pragma unroll
        for (int i = 0; i < 4; i++) {
            #pragma unroll
            for (int r = 0; r < 4; r++) {
                int m = row0 + wm + i*16 + r4 + r;
                float p = mk ? __expf(acc[i][j][r]*st) : 0.0f;
                P[((size_t)z*SEQ + m)*SEQ + n] = f2bfbits(p);
            }
        }
    }
}

// ---- row sums of P -> lbuf (fp32) ----
__global__ __launch_bounds__(256) void rowsum_kernel(const unsigned short* __restrict__ P,
                                                     float* __restrict__ lbuf) {
    int row = blockIdx.x*4 + (threadIdx.x >> 6);
    int lane = threadIdx.x & 63;
    const unsigned short* pr = P + (size_t)row*SEQ;
    float s = 0.f;
    for (int c = lane*8; c < SEQ; c += 64*8) {
        ushort4 a = *(const ushort4*)&pr[c];
        ushort4 b = *(const ushort4*)&pr[c+4];
        s += bfbits2f(a.x)+bfbits2f(a.y)+bfbits2f(a.z)+bfbits2f(a.w)
           + bfbits2f(b.x)+bfbits2f(b.y)+bfbits2f(b.z)+bfbits2f(b.w);
    }
    #pragma unroll
    for (int off = 32; off > 0; off >>= 1) s += __shfl_down(s, off, 64);
    if (lane == 0) lbuf[row] = s;
}

// ---- K3: ctx = P@v / l; g = u*ctx written in-place over u ----
__global__ __launch_bounds__(256) void pv_mfma(
    const unsigned short* __restrict__ P, const unsigned short* __restrict__ vT,
    const float* __restrict__ lbuf, unsigned short* __restrict__ u)
{
    __shared__ __align__(16) unsigned short As[128*32];
    __shared__ __align__(16) unsigned short Bs[128*32];
    const int tid = threadIdx.x;
    const int z = blockIdx.z;
    const int row0 = blockIdx.y*128, col0 = blockIdx.x*128;
    f32x4 acc[4][4];
    #pragma unroll
    for (int i = 0; i < 4; i++)
        #pragma unroll
        for (int j = 0; j < 4; j++)
            acc[i][j] = (f32x4){0.f,0.f,0.f,0.f};
    mfma_core(P + ((size_t)z*SEQ + row0)*SEQ, SEQ, vT + ((size_t)z*INTER + col0)*SEQ, SEQ,
              As, Bs, acc, tid, SEQ);
    EPILOG_IDX
    #pragma unroll
    for (int i = 0; i < 4; i++) {
        #pragma unroll
        for (int r = 0; r < 4; r++) {
            int gm = z*SEQ + row0 + wm + i*16 + r4 + r;
            float linv = 1.0f / lbuf[gm];
            #pragma unroll
            for (int j = 0; j < 4; j++) {
                int n = col0 + wn + j*16 + cn;
                size_t idx = (size_t)gm*INTER + n;
                float uu = bfbits2f(u[idx]);
                u[idx] = f2bfbits(uu * acc[i][j][r] * linv);
            }
        }
    }
}

// ---- K4: out = g@Wo + bo (fp32 out) ----
__global__ __launch_bounds__(256) void gemm2_mfma(
    const unsigned short* __restrict__ g, const unsigned short* __restrict__ WoT,
    const float* __restrict__ bo, float* __restrict__ out)
{
    __shared__ __align__(16) unsigned short As[128*32];
    __shared__ __align__(16) unsigned short Bs[128*32];
    const int tid = threadIdx.x;
    const int row0 = blockIdx.y*128, col0 = blockIdx.x*128;
    f32x4 acc[4][4];
    #pragma unroll
    for (int i = 0; i < 4; i++)
        #pragma unroll
        for (int j = 0; j < 4; j++)
            acc[i][j] = (f32x4){0.f,0.f,0.f,0.f};
    mfma_core(g + (size_t)row0*INTER, INTER, WoT + (size_t)col0*INTER, INTER,
              As, Bs, acc, tid, INTER);
    EPILOG_IDX
    #pragma unroll
    for (int j = 0; j < 4; j++) {
        int n = col0 + wn + j*16 + cn;
        float bon = bo[n];
        #pragma unroll
        for (int i = 0; i < 4; i++) {
            #pragma unroll
            for (int r = 0; r < 4; r++) {
                int m = row0 + wm + i*16 + r4 + r;
                out[(size_t)m*HIDDEN + n] = acc[i][j][r] + bon;
            }
        }
    }
}

extern "C" void kernel_launch(void* const* d_in, const int* in_sizes, int n_in,
                              void* d_out, int out_size, void* d_ws, size_t ws_size,
                              hipStream_t stream)
{
    const float* X     = (const float*)d_in[0];
    const int*   mask  = (const int*)d_in[1];
    const float* Wi    = (const float*)d_in[3];
    const float* bi    = (const float*)d_in[4];
    const float* gamma = (const float*)d_in[5];
    const float* beta  = (const float*)d_in[6];
    const float* Wo    = (const float*)d_in[7];
    const float* bo    = (const float*)d_in[8];
    float* out = (float*)d_out;

    // workspace (halfwords unless noted)
    unsigned short* Xb  = (unsigned short*)d_ws;            // 8192*768
    unsigned short* WiT = Xb  + (size_t)MTOT*HIDDEN;        // 3200*768
    unsigned short* WoT = WiT + (size_t)ETOT*HIDDEN;        // 768*1536
    unsigned short* u   = WoT + (size_t)HIDDEN*INTER;       // 8192*1536
    unsigned short* v   = u   + (size_t)MTOT*INTER;         // 8192*1536
    unsigned short* vT  = v   + (size_t)MTOT*INTER;         // 4*1536*2048
    unsigned short* qb  = vT  + (size_t)MTOT*INTER;         // 8192*128
    unsigned short* kb  = qb  + (size_t)MTOT*KEY;           // 8192*128
    unsigned short* P   = kb  + (size_t)MTOT*KEY;           // 4*2048*2048
    float* lb  = (float*)(P + (size_t)NB*SEQ*SEQ);          // 8192
    float* scb = lb + MTOT;                                 // 4

    scale_kernel<<<NB, 256, 0, stream>>>(mask, scb);
    cvt_bf16_kernel<<<(MTOT*HIDDEN/4 + 255)/256, 256, 0, stream>>>(X, Xb, MTOT*HIDDEN/4);
    transpose_cvt<<<dim3(ETOT/32, HIDDEN/32), 256, 0, stream>>>(Wi, WiT, HIDDEN, ETOT);
    transpose_cvt<<<dim3(HIDDEN/32, INTER/32), 256, 0, stream>>>(Wo, WoT, INTER, HIDDEN);
    gemm1_mfma<<<dim3(ETOT/128, MTOT/128), 256, 0, stream>>>(Xb, WiT, bi, gamma, beta, u, v, qb, kb);
    transpose_v<<<dim3(INTER/32, SEQ/32, NB), 256, 0, stream>>>(v, vT);
    attn_mfma<<<dim3(SEQ/128, SEQ/128, NB), 256, 0, stream>>>(qb, kb, mask, scb, P);
    rowsum_kernel<<<MTOT/4, 256, 0, stream>>>(P, lb);
    pv_mfma<<<dim3(INTER/128, SEQ/128, NB), 256, 0, stream>>>(P, vT, lb, u);
    gemm2_mfma<<<dim3(HIDDEN/128, MTOT/128), 256, 0, stream>>>(u, WoT, bo, out);
}

// Round 3
// 318.299 us; speedup vs baseline: 5.4662x; 1.0320x over previous
//
#include <hip/hip_runtime.h>
#include <math.h>

#define HIDDEN 768
#define KEY    128
#define INTER  1536
#define NB     4
#define SEQ    2048
#define MTOT   (NB*SEQ)          // 8192
#define ETOT   (2*INTER+KEY)     // 3200
#define CS     136               // C-tile LDS stride in halfwords (16B-aligned rows, bank-clean)

typedef short bf16x8 __attribute__((ext_vector_type(8)));
typedef float f32x4  __attribute__((ext_vector_type(4)));
typedef unsigned short u16x8 __attribute__((ext_vector_type(8)));

// ---- bf16 bit helpers (round-to-nearest-even) ----
__device__ __forceinline__ unsigned short f2bfbits(float x) {
    union { float f; unsigned int u; } a; a.f = x;
    unsigned int r = a.u + 0x7fffu + ((a.u >> 16) & 1u);
    return (unsigned short)(r >> 16);
}
__device__ __forceinline__ float bfbits2f(unsigned short b) {
    union { float f; unsigned int u; } a; a.u = ((unsigned int)b) << 16;
    return a.f;
}

// async global->LDS, 16 bytes per lane
__device__ __forceinline__ void gl2lds16(const unsigned short* g, unsigned short* l) {
    __builtin_amdgcn_global_load_lds(
        (const __attribute__((address_space(1))) unsigned int*)g,
        (__attribute__((address_space(3))) unsigned int*)l, 16, 0, 0);
}

// ---- K0: per-batch softmax length scale ----
__global__ __launch_bounds__(256) void scale_kernel(const int* __restrict__ mask,
                                                    float* __restrict__ scaleb) {
    __shared__ int red[256];
    int b = blockIdx.x;
    int s = 0;
    for (int j = threadIdx.x; j < SEQ; j += 256)
        s += (mask[b*SEQ + j] != 0) ? 1 : 0;
    red[threadIdx.x] = s;
    __syncthreads();
    for (int step = 128; step > 0; step >>= 1) {
        if (threadIdx.x < step) red[threadIdx.x] += red[threadIdx.x + step];
        __syncthreads();
    }
    if (threadIdx.x == 0) {
        float l = fmaxf((float)red[0], 1.0f);
        scaleb[b] = logf(l) / logf(512.0f);
    }
}

// ---- fp32 -> bf16 elementwise ----
__global__ __launch_bounds__(256) void cvt_bf16_kernel(const float* __restrict__ in,
                                                       unsigned short* __restrict__ out, int n4) {
    int i = blockIdx.x*256 + threadIdx.x;
    if (i < n4) {
        float4 v = ((const float4*)in)[i];
        ushort4 o;
        o.x = f2bfbits(v.x); o.y = f2bfbits(v.y);
        o.z = f2bfbits(v.z); o.w = f2bfbits(v.w);
        ((ushort4*)out)[i] = o;
    }
}

// ---- transpose fp32 [R][C] -> bf16 [C][R] ----
__global__ __launch_bounds__(256) void transpose_cvt(const float* __restrict__ in,
                                                     unsigned short* __restrict__ out,
                                                     int R, int C) {
    __shared__ unsigned short tile[32][33];
    int c0 = blockIdx.x*32, r0 = blockIdx.y*32;
    int tx = threadIdx.x & 31, ty4 = (threadIdx.x >> 5)*4;
    #pragma unroll
    for (int rr = 0; rr < 4; rr++) {
        int r = ty4 + rr;
        tile[r][tx] = f2bfbits(in[(size_t)(r0+r)*C + c0+tx]);
    }
    __syncthreads();
    #pragma unroll
    for (int rr = 0; rr < 4; rr++) {
        int r = ty4 + rr;
        out[(size_t)(c0+r)*R + r0+tx] = tile[tx][r];
    }
}

// ---- shared MFMA K-loop: 128x128 tile, BK=32, A and B^T both [row][K] bf16 ----
__device__ __forceinline__ void mfma_core(
    const unsigned short* __restrict__ Abase, int lda,
    const unsigned short* __restrict__ Bbase, int ldb,
    unsigned short* As, unsigned short* Bs,
    f32x4 acc[4][4], int tid, int ktot)
{
    const int lane = tid & 63, wave = tid >> 6;
    const int wm = (wave >> 1) << 6, wn = (wave & 1) << 6;
    const int lm = lane & 15;
    const int q8 = (lane >> 4) << 3;
    const int row_a = tid >> 2, col_a = (tid & 3) << 3;   // staging round 0
    const int row_b = row_a + 64;                          // staging round 1

    for (int k0 = 0; k0 < ktot; k0 += 32) {
        if (k0) __syncthreads();
        gl2lds16(Abase + (size_t)row_a*lda + k0 + col_a, As + tid*8);
        gl2lds16(Bbase + (size_t)row_a*ldb + k0 + col_a, Bs + tid*8);
        gl2lds16(Abase + (size_t)row_b*lda + k0 + col_a, As + (tid+256)*8);
        gl2lds16(Bbase + (size_t)row_b*ldb + k0 + col_a, Bs + (tid+256)*8);
        __syncthreads();
        bf16x8 af[4], bfr[4];
        #pragma unroll
        for (int i = 0; i < 4; i++)
            af[i] = *(const bf16x8*)&As[(wm + i*16 + lm)*32 + q8];
        #pragma unroll
        for (int j = 0; j < 4; j++)
            bfr[j] = *(const bf16x8*)&Bs[(wn + j*16 + lm)*32 + q8];
        #pragma unroll
        for (int i = 0; i < 4; i++)
            #pragma unroll
            for (int j = 0; j < 4; j++)
                acc[i][j] = __builtin_amdgcn_mfma_f32_16x16x32_bf16(af[i], bfr[j], acc[i][j], 0, 0, 0);
    }
}

#define EPILOG_IDX \
    const int lane = tid & 63, wave = tid >> 6; \
    const int wm = (wave >> 1) << 6, wn = (wave & 1) << 6; \
    const int cn = lane & 15, r4 = (lane >> 4) << 2;

// ---- K1: h = silu(X@Wi + bi); u row-major, vT transposed, q/k (gamma/beta) ----
__global__ __launch_bounds__(256) void gemm1_mfma(
    const unsigned short* __restrict__ Xb, const unsigned short* __restrict__ WiT,
    const float* __restrict__ bi, const float* __restrict__ gamma, const float* __restrict__ beta,
    unsigned short* __restrict__ u, unsigned short* __restrict__ vT,
    unsigned short* __restrict__ qb, unsigned short* __restrict__ kb)
{
    __shared__ __align__(16) unsigned short smem[128*CS];
    unsigned short* As = smem;
    unsigned short* Bs = smem + 4096;
    const int tid = threadIdx.x;
    const int row0 = blockIdx.y*128, col0 = blockIdx.x*128;
    f32x4 acc[4][4];
    #pragma unroll
    for (int i = 0; i < 4; i++)
        #pragma unroll
        for (int j = 0; j < 4; j++)
            acc[i][j] = (f32x4){0.f,0.f,0.f,0.f};
    mfma_core(Xb + (size_t)row0*HIDDEN, HIDDEN, WiT + (size_t)col0*HIDDEN, HIDDEN,
              As, Bs, acc, tid, HIDDEN);
    EPILOG_IDX
    __syncthreads();   // all waves done reading As/Bs
    // phase A: bias + silu -> C-tile in LDS
    #pragma unroll
    for (int j = 0; j < 4; j++) {
        int nl = wn + j*16 + cn;
        float bin = bi[col0 + nl];
        #pragma unroll
        for (int i = 0; i < 4; i++) {
            #pragma unroll
            for (int r = 0; r < 4; r++) {
                int rowl = wm + i*16 + r4 + r;
                float x = acc[i][j][r] + bin;
                float h = x / (1.0f + __expf(-x));
                smem[rowl*CS + nl] = f2bfbits(h);
            }
        }
    }
    __syncthreads();
    // phase B: coalesced stores
    if (col0 < INTER) {                       // u, row-major
        #pragma unroll
        for (int rnd = 0; rnd < 8; rnd++) {
            int row = rnd*16 + (tid>>4);
            int col = (tid&15)*8;
            u16x8 h = *(const u16x8*)&smem[row*CS + col];
            *(u16x8*)&u[(size_t)(row0+row)*INTER + col0 + col] = h;
        }
    } else if (col0 < 2*INTER) {              // v, stored transposed -> vT[b][INTER][SEQ]
        int c = tid >> 1;                     // local col 0..127
        int half = tid & 1;                   // row half
        int b = row0 / SEQ;
        int srow = row0 - b*SEQ + half*64;
        size_t base = ((size_t)b*INTER + (col0 - INTER) + c)*SEQ + srow;
        #pragma unroll
        for (int k = 0; k < 8; k++) {
            u16x8 h;
            #pragma unroll
            for (int t = 0; t < 8; t++)
                h[t] = smem[(half*64 + k*8 + t)*CS + c];
            *(u16x8*)&vT[base + k*8] = h;
        }
    } else {                                  // q/k block (col0 == 2*INTER)
        #pragma unroll
        for (int rnd = 0; rnd < 8; rnd++) {
            int row = rnd*16 + (tid>>4);
            int col = (tid&15)*8;
            u16x8 h = *(const u16x8*)&smem[row*CS + col];
            int m = row0 + row;
            u16x8 qo, ko;
            #pragma unroll
            for (int t = 0; t < 8; t++) {
                float hv = bfbits2f(h[t]);
                qo[t] = f2bfbits(hv*gamma[col+t]       + beta[col+t]);
                ko[t] = f2bfbits(hv*gamma[KEY+col+t]   + beta[KEY+col+t]);
            }
            *(u16x8*)&qb[(size_t)m*KEY + col] = qo;
            *(u16x8*)&kb[(size_t)m*KEY + col] = ko;
        }
    }
}

// ---- K2: P = exp(scale * q@k^T) masked, bf16, unnormalized ----
__global__ __launch_bounds__(256) void attn_mfma(
    const unsigned short* __restrict__ qb, const unsigned short* __restrict__ kb,
    const int* __restrict__ mask, const float* __restrict__ scaleb,
    unsigned short* __restrict__ P)
{
    __shared__ __align__(16) unsigned short smem[128*CS];
    unsigned short* As = smem;
    unsigned short* Bs = smem + 4096;
    const int tid = threadIdx.x;
    const int z = blockIdx.z;
    const int row0 = blockIdx.y*128, col0 = blockIdx.x*128;
    f32x4 acc[4][4];
    #pragma unroll
    for (int i = 0; i < 4; i++)
        #pragma unroll
        for (int j = 0; j < 4; j++)
            acc[i][j] = (f32x4){0.f,0.f,0.f,0.f};
    mfma_core(qb + ((size_t)z*SEQ + row0)*KEY, KEY, kb + ((size_t)z*SEQ + col0)*KEY, KEY,
              As, Bs, acc, tid, KEY);
    const float st = scaleb[z] * 0.08838834764831845f;  // 1/sqrt(128)
    EPILOG_IDX
    __syncthreads();
    #pragma unroll
    for (int j = 0; j < 4; j++) {
        int nl = wn + j*16 + cn;
        float mkf = (mask[z*SEQ + col0 + nl] != 0) ? 1.0f : 0.0f;
        #pragma unroll
        for (int i = 0; i < 4; i++) {
            #pragma unroll
            for (int r = 0; r < 4; r++) {
                int rowl = wm + i*16 + r4 + r;
                float p = mkf * __expf(acc[i][j][r]*st);
                smem[rowl*CS + nl] = f2bfbits(p);
            }
        }
    }
    __syncthreads();
    #pragma unroll
    for (int rnd = 0; rnd < 8; rnd++) {
        int row = rnd*16 + (tid>>4);
        int col = (tid&15)*8;
        u16x8 h = *(const u16x8*)&smem[row*CS + col];
        *(u16x8*)&P[((size_t)z*SEQ + row0 + row)*SEQ + col0 + col] = h;
    }
}

// ---- row sums of P -> lbuf (fp32) ----
__global__ __launch_bounds__(256) void rowsum_kernel(const unsigned short* __restrict__ P,
                                                     float* __restrict__ lbuf) {
    int row = blockIdx.x*4 + (threadIdx.x >> 6);
    int lane = threadIdx.x & 63;
    const unsigned short* pr = P + (size_t)row*SEQ;
    float s = 0.f;
    for (int c = lane*8; c < SEQ; c += 64*8) {
        ushort4 a = *(const ushort4*)&pr[c];
        ushort4 b = *(const ushort4*)&pr[c+4];
        s += bfbits2f(a.x)+bfbits2f(a.y)+bfbits2f(a.z)+bfbits2f(a.w)
           + bfbits2f(b.x)+bfbits2f(b.y)+bfbits2f(b.z)+bfbits2f(b.w);
    }
    #pragma unroll
    for (int off = 32; off > 0; off >>= 1) s += __shfl_down(s, off, 64);
    if (lane == 0) lbuf[row] = s;
}

// ---- K3: ctx = P@v / l; g = u*ctx written in-place over u ----
__global__ __launch_bounds__(256) void pv_mfma(
    const unsigned short* __restrict__ P, const unsigned short* __restrict__ vT,
    const float* __restrict__ lbuf, unsigned short* __restrict__ u)
{
    __shared__ __align__(16) unsigned short smem[128*CS];
    unsigned short* As = smem;
    unsigned short* Bs = smem + 4096;
    const int tid = threadIdx.x;
    const int z = blockIdx.z;
    const int row0 = blockIdx.y*128, col0 = blockIdx.x*128;
    f32x4 acc[4][4];
    #pragma unroll
    for (int i = 0; i < 4; i++)
        #pragma unroll
        for (int j = 0; j < 4; j++)
            acc[i][j] = (f32x4){0.f,0.f,0.f,0.f};
    mfma_core(P + ((size_t)z*SEQ + row0)*SEQ, SEQ, vT + ((size_t)z*INTER + col0)*SEQ, SEQ,
              As, Bs, acc, tid, SEQ);
    EPILOG_IDX
    __syncthreads();
    #pragma unroll
    for (int j = 0; j < 4; j++) {
        int nl = wn + j*16 + cn;
        #pragma unroll
        for (int i = 0; i < 4; i++) {
            #pragma unroll
            for (int r = 0; r < 4; r++) {
                int rowl = wm + i*16 + r4 + r;
                smem[rowl*CS + nl] = f2bfbits(acc[i][j][r]);
            }
        }
    }
    __syncthreads();
    #pragma unroll
    for (int rnd = 0; rnd < 8; rnd++) {
        int row = rnd*16 + (tid>>4);
        int col = (tid&15)*8;
        int m = z*SEQ + row0 + row;
        float linv = 1.0f / lbuf[m];
        u16x8 cx = *(const u16x8*)&smem[row*CS + col];
        size_t idx = (size_t)m*INTER + col0 + col;
        u16x8 uu = *(const u16x8*)&u[idx];
        u16x8 g;
        #pragma unroll
        for (int t = 0; t < 8; t++)
            g[t] = f2bfbits(bfbits2f(uu[t]) * bfbits2f(cx[t]) * linv);
        *(u16x8*)&u[idx] = g;
    }
}

// ---- K4: out = g@Wo + bo (fp32 out, direct stores) ----
__global__ __launch_bounds__(256) void gemm2_mfma(
    const unsigned short* __restrict__ g, const unsigned short* __restrict__ WoT,
    const float* __restrict__ bo, float* __restrict__ out)
{
    __shared__ __align__(16) unsigned short As[128*32];
    __shared__ __align__(16) unsigned short Bs[128*32];
    const int tid = threadIdx.x;
    const int row0 = blockIdx.y*128, col0 = blockIdx.x*128;
    f32x4 acc[4][4];
    #pragma unroll
    for (int i = 0; i < 4; i++)
        #pragma unroll
        for (int j = 0; j < 4; j++)
            acc[i][j] = (f32x4){0.f,0.f,0.f,0.f};
    mfma_core(g + (size_t)row0*INTER, INTER, WoT + (size_t)col0*INTER, INTER,
              As, Bs, acc, tid, INTER);
    EPILOG_IDX
    #pragma unroll
    for (int j = 0; j < 4; j++) {
        int n = col0 + wn + j*16 + cn;
        float bon = bo[n];
        #pragma unroll
        for (int i = 0; i < 4; i++) {
            #pragma unroll
            for (int r = 0; r < 4; r++) {
                int m = row0 + wm + i*16 + r4 + r;
                out[(size_t)m*HIDDEN + n] = acc[i][j][r] + bon;
            }
        }
    }
}

extern "C" void kernel_launch(void* const* d_in, const int* in_sizes, int n_in,
                              void* d_out, int out_size, void* d_ws, size_t ws_size,
                              hipStream_t stream)
{
    const float* X     = (const float*)d_in[0];
    const int*   mask  = (const int*)d_in[1];
    const float* Wi    = (const float*)d_in[3];
    const float* bi    = (const float*)d_in[4];
    const float* gamma = (const float*)d_in[5];
    const float* beta  = (const float*)d_in[6];
    const float* Wo    = (const float*)d_in[7];
    const float* bo    = (const float*)d_in[8];
    float* out = (float*)d_out;

    // workspace (halfwords unless noted)
    unsigned short* Xb  = (unsigned short*)d_ws;            // 8192*768
    unsigned short* WiT = Xb  + (size_t)MTOT*HIDDEN;        // 3200*768
    unsigned short* WoT = WiT + (size_t)ETOT*HIDDEN;        // 768*1536
    unsigned short* u   = WoT + (size_t)HIDDEN*INTER;       // 8192*1536
    unsigned short* vT  = u   + (size_t)MTOT*INTER;         // 4*1536*2048
    unsigned short* qb  = vT  + (size_t)MTOT*INTER;         // 8192*128
    unsigned short* kb  = qb  + (size_t)MTOT*KEY;           // 8192*128
    unsigned short* P   = kb  + (size_t)MTOT*KEY;           // 4*2048*2048
    float* lb  = (float*)(P + (size_t)NB*SEQ*SEQ);          // 8192
    float* scb = lb + MTOT;                                 // 4

    scale_kernel<<<NB, 256, 0, stream>>>(mask, scb);
    cvt_bf16_kernel<<<(MTOT*HIDDEN/4 + 255)/256, 256, 0, stream>>>(X, Xb, MTOT*HIDDEN/4);
    transpose_cvt<<<dim3(ETOT/32, HIDDEN/32), 256, 0, stream>>>(Wi, WiT, HIDDEN, ETOT);
    transpose_cvt<<<dim3(HIDDEN/32, INTER/32), 256, 0, stream>>>(Wo, WoT, INTER, HIDDEN);
    gemm1_mfma<<<dim3(ETOT/128, MTOT/128), 256, 0, stream>>>(Xb, WiT, bi, gamma, beta, u, vT, qb, kb);
    attn_mfma<<<dim3(SEQ/128, SEQ/128, NB), 256, 0, stream>>>(qb, kb, mask, scb, P);
    rowsum_kernel<<<MTOT/4, 256, 0, stream>>>(P, lb);
    pv_mfma<<<dim3(INTER/128, SEQ/128, NB), 256, 0, stream>>>(P, vT, lb, u);
    gemm2_mfma<<<dim3(HIDDEN/128, MTOT/128), 256, 0, stream>>>(u, WoT, bo, out);
}

// Round 4
// 301.915 us; speedup vs baseline: 5.7628x; 1.0543x over previous
//
#include <hip/hip_runtime.h>
#include <math.h>

#define HIDDEN 768
#define KEY    128
#define INTER  1536
#define NB     4
#define SEQ    2048
#define MTOT   (NB*SEQ)          // 8192
#define ETOT   (2*INTER+KEY)     // 3200
#define CS     136               // C-tile LDS stride in halfwords

typedef short bf16x8 __attribute__((ext_vector_type(8)));
typedef float f32x4  __attribute__((ext_vector_type(4)));
typedef unsigned short u16x8 __attribute__((ext_vector_type(8)));

__device__ __forceinline__ unsigned short f2bfbits(float x) {
    union { float f; unsigned int u; } a; a.f = x;
    unsigned int r = a.u + 0x7fffu + ((a.u >> 16) & 1u);
    return (unsigned short)(r >> 16);
}
__device__ __forceinline__ float bfbits2f(unsigned short b) {
    union { float f; unsigned int u; } a; a.u = ((unsigned int)b) << 16;
    return a.f;
}

__device__ __forceinline__ void gl2lds16(const unsigned short* g, unsigned short* l) {
    __builtin_amdgcn_global_load_lds(
        (const __attribute__((address_space(1))) unsigned int*)g,
        (__attribute__((address_space(3))) unsigned int*)l, 16, 0, 0);
}

// ---- K0: per-batch softmax length scale ----
__global__ __launch_bounds__(256) void scale_kernel(const int* __restrict__ mask,
                                                    float* __restrict__ scaleb) {
    __shared__ int red[256];
    int b = blockIdx.x;
    int s = 0;
    for (int j = threadIdx.x; j < SEQ; j += 256)
        s += (mask[b*SEQ + j] != 0) ? 1 : 0;
    red[threadIdx.x] = s;
    __syncthreads();
    for (int step = 128; step > 0; step >>= 1) {
        if (threadIdx.x < step) red[threadIdx.x] += red[threadIdx.x + step];
        __syncthreads();
    }
    if (threadIdx.x == 0) {
        float l = fmaxf((float)red[0], 1.0f);
        scaleb[b] = logf(l) / logf(512.0f);
    }
}

// ---- fp32 -> bf16 elementwise ----
__global__ __launch_bounds__(256) void cvt_bf16_kernel(const float* __restrict__ in,
                                                       unsigned short* __restrict__ out, int n4) {
    int i = blockIdx.x*256 + threadIdx.x;
    if (i < n4) {
        float4 v = ((const float4*)in)[i];
        ushort4 o;
        o.x = f2bfbits(v.x); o.y = f2bfbits(v.y);
        o.z = f2bfbits(v.z); o.w = f2bfbits(v.w);
        ((ushort4*)out)[i] = o;
    }
}

// ---- transpose fp32 [R][C] -> bf16 [C][R] ----
__global__ __launch_bounds__(256) void transpose_cvt(const float* __restrict__ in,
                                                     unsigned short* __restrict__ out,
                                                     int R, int C) {
    __shared__ unsigned short tile[32][33];
    int c0 = blockIdx.x*32, r0 = blockIdx.y*32;
    int tx = threadIdx.x & 31, ty4 = (threadIdx.x >> 5)*4;
    #pragma unroll
    for (int rr = 0; rr < 4; rr++) {
        int r = ty4 + rr;
        tile[r][tx] = f2bfbits(in[(size_t)(r0+r)*C + c0+tx]);
    }
    __syncthreads();
    #pragma unroll
    for (int rr = 0; rr < 4; rr++) {
        int r = ty4 + rr;
        out[(size_t)(c0+r)*R + r0+tx] = tile[tx][r];
    }
}

// ---- shared MFMA K-loop: 128x128 tile, BK=64 (two BK=32 sub-stages, one barrier
// pair per 64) — A and B^T both [row][K] bf16. As/Bs each 8192 hw (16 KB). ----
__device__ __forceinline__ void mfma_core(
    const unsigned short* __restrict__ Abase, int lda,
    const unsigned short* __restrict__ Bbase, int ldb,
    unsigned short* As, unsigned short* Bs,
    f32x4 acc[4][4], int tid, int ktot)
{
    const int lane = tid & 63, wave = tid >> 6;
    const int wm = (wave >> 1) << 6, wn = (wave & 1) << 6;
    const int lm = lane & 15;
    const int q8 = (lane >> 4) << 3;
    const int row_a = tid >> 2, col_a = (tid & 3) << 3;
    const int row_b = row_a + 64;

    for (int k0 = 0; k0 < ktot; k0 += 64) {
        if (k0) __syncthreads();
        // sub-stage 0: k0..k0+31
        gl2lds16(Abase + (size_t)row_a*lda + k0 + col_a,        As + tid*8);
        gl2lds16(Abase + (size_t)row_b*lda + k0 + col_a,        As + (tid+256)*8);
        gl2lds16(Bbase + (size_t)row_a*ldb + k0 + col_a,        Bs + tid*8);
        gl2lds16(Bbase + (size_t)row_b*ldb + k0 + col_a,        Bs + (tid+256)*8);
        // sub-stage 1: k0+32..k0+63
        gl2lds16(Abase + (size_t)row_a*lda + k0+32 + col_a,     As + 4096 + tid*8);
        gl2lds16(Abase + (size_t)row_b*lda + k0+32 + col_a,     As + 4096 + (tid+256)*8);
        gl2lds16(Bbase + (size_t)row_a*ldb + k0+32 + col_a,     Bs + 4096 + tid*8);
        gl2lds16(Bbase + (size_t)row_b*ldb + k0+32 + col_a,     Bs + 4096 + (tid+256)*8);
        __syncthreads();
        #pragma unroll
        for (int h = 0; h < 2; h++) {
            const unsigned short* Ah = As + h*4096;
            const unsigned short* Bh = Bs + h*4096;
            bf16x8 af[4], bfr[4];
            #pragma unroll
            for (int i = 0; i < 4; i++)
                af[i] = *(const bf16x8*)&Ah[(wm + i*16 + lm)*32 + q8];
            #pragma unroll
            for (int j = 0; j < 4; j++)
                bfr[j] = *(const bf16x8*)&Bh[(wn + j*16 + lm)*32 + q8];
            #pragma unroll
            for (int i = 0; i < 4; i++)
                #pragma unroll
                for (int j = 0; j < 4; j++)
                    acc[i][j] = __builtin_amdgcn_mfma_f32_16x16x32_bf16(af[i], bfr[j], acc[i][j], 0, 0, 0);
        }
    }
}

#define EPILOG_IDX \
    const int lane = tid & 63, wave = tid >> 6; \
    const int wm = (wave >> 1) << 6, wn = (wave & 1) << 6; \
    const int cn = lane & 15, r4 = (lane >> 4) << 2;

// ---- K1: h = silu(X@Wi + bi); u row-major, vT transposed, q/k (gamma/beta) ----
__global__ __launch_bounds__(256) void gemm1_mfma(
    const unsigned short* __restrict__ Xb, const unsigned short* __restrict__ WiT,
    const float* __restrict__ bi, const float* __restrict__ gamma, const float* __restrict__ beta,
    unsigned short* __restrict__ u, unsigned short* __restrict__ vT,
    unsigned short* __restrict__ qb, unsigned short* __restrict__ kb)
{
    __shared__ __align__(16) unsigned short smem[128*CS];   // 34816 B; staging aliased below
    unsigned short* As = smem;                // 8192 hw
    unsigned short* Bs = smem + 8192;         // 8192 hw
    const int tid = threadIdx.x;
    const int row0 = blockIdx.y*128, col0 = blockIdx.x*128;
    f32x4 acc[4][4];
    #pragma unroll
    for (int i = 0; i < 4; i++)
        #pragma unroll
        for (int j = 0; j < 4; j++)
            acc[i][j] = (f32x4){0.f,0.f,0.f,0.f};
    mfma_core(Xb + (size_t)row0*HIDDEN, HIDDEN, WiT + (size_t)col0*HIDDEN, HIDDEN,
              As, Bs, acc, tid, HIDDEN);
    EPILOG_IDX
    __syncthreads();
    #pragma unroll
    for (int j = 0; j < 4; j++) {
        int nl = wn + j*16 + cn;
        float bin = bi[col0 + nl];
        #pragma unroll
        for (int i = 0; i < 4; i++) {
            #pragma unroll
            for (int r = 0; r < 4; r++) {
                int rowl = wm + i*16 + r4 + r;
                float x = acc[i][j][r] + bin;
                float h = x / (1.0f + __expf(-x));
                smem[rowl*CS + nl] = f2bfbits(h);
            }
        }
    }
    __syncthreads();
    if (col0 < INTER) {                       // u, row-major
        #pragma unroll
        for (int rnd = 0; rnd < 8; rnd++) {
            int row = rnd*16 + (tid>>4);
            int col = (tid&15)*8;
            u16x8 h = *(const u16x8*)&smem[row*CS + col];
            *(u16x8*)&u[(size_t)(row0+row)*INTER + col0 + col] = h;
        }
    } else if (col0 < 2*INTER) {              // v, stored transposed -> vT[b][INTER][SEQ]
        int c = tid >> 1;
        int half = tid & 1;
        int b = row0 / SEQ;
        int srow = row0 - b*SEQ + half*64;
        size_t base = ((size_t)b*INTER + (col0 - INTER) + c)*SEQ + srow;
        #pragma unroll
        for (int k = 0; k < 8; k++) {
            u16x8 h;
            #pragma unroll
            for (int t = 0; t < 8; t++)
                h[t] = smem[(half*64 + k*8 + t)*CS + c];
            *(u16x8*)&vT[base + k*8] = h;
        }
    } else {                                  // q/k block
        #pragma unroll
        for (int rnd = 0; rnd < 8; rnd++) {
            int row = rnd*16 + (tid>>4);
            int col = (tid&15)*8;
            u16x8 h = *(const u16x8*)&smem[row*CS + col];
            int m = row0 + row;
            u16x8 qo, ko;
            #pragma unroll
            for (int t = 0; t < 8; t++) {
                float hv = bfbits2f(h[t]);
                qo[t] = f2bfbits(hv*gamma[col+t]     + beta[col+t]);
                ko[t] = f2bfbits(hv*gamma[KEY+col+t] + beta[KEY+col+t]);
            }
            *(u16x8*)&qb[(size_t)m*KEY + col] = qo;
            *(u16x8*)&kb[(size_t)m*KEY + col] = ko;
        }
    }
}

// ---- K2: P = exp(scale * q@k^T) masked, bf16, unnormalized ----
__global__ __launch_bounds__(256) void attn_mfma(
    const unsigned short* __restrict__ qb, const unsigned short* __restrict__ kb,
    const int* __restrict__ mask, const float* __restrict__ scaleb,
    unsigned short* __restrict__ P)
{
    __shared__ __align__(16) unsigned short smem[128*CS];
    unsigned short* As = smem;
    unsigned short* Bs = smem + 8192;
    const int tid = threadIdx.x;
    const int z = blockIdx.z;
    const int row0 = blockIdx.y*128, col0 = blockIdx.x*128;
    f32x4 acc[4][4];
    #pragma unroll
    for (int i = 0; i < 4; i++)
        #pragma unroll
        for (int j = 0; j < 4; j++)
            acc[i][j] = (f32x4){0.f,0.f,0.f,0.f};
    mfma_core(qb + ((size_t)z*SEQ + row0)*KEY, KEY, kb + ((size_t)z*SEQ + col0)*KEY, KEY,
              As, Bs, acc, tid, KEY);
    const float st = scaleb[z] * 0.08838834764831845f;
    EPILOG_IDX
    __syncthreads();
    #pragma unroll
    for (int j = 0; j < 4; j++) {
        int nl = wn + j*16 + cn;
        float mkf = (mask[z*SEQ + col0 + nl] != 0) ? 1.0f : 0.0f;
        #pragma unroll
        for (int i = 0; i < 4; i++) {
            #pragma unroll
            for (int r = 0; r < 4; r++) {
                int rowl = wm + i*16 + r4 + r;
                float p = mkf * __expf(acc[i][j][r]*st);
                smem[rowl*CS + nl] = f2bfbits(p);
            }
        }
    }
    __syncthreads();
    #pragma unroll
    for (int rnd = 0; rnd < 8; rnd++) {
        int row = rnd*16 + (tid>>4);
        int col = (tid&15)*8;
        u16x8 h = *(const u16x8*)&smem[row*CS + col];
        *(u16x8*)&P[((size_t)z*SEQ + row0 + row)*SEQ + col0 + col] = h;
    }
}

// ---- row sums of P -> lbuf (fp32) ----
__global__ __launch_bounds__(256) void rowsum_kernel(const unsigned short* __restrict__ P,
                                                     float* __restrict__ lbuf) {
    int row = blockIdx.x*4 + (threadIdx.x >> 6);
    int lane = threadIdx.x & 63;
    const unsigned short* pr = P + (size_t)row*SEQ;
    float s = 0.f;
    for (int c = lane*8; c < SEQ; c += 64*8) {
        ushort4 a = *(const ushort4*)&pr[c];
        ushort4 b = *(const ushort4*)&pr[c+4];
        s += bfbits2f(a.x)+bfbits2f(a.y)+bfbits2f(a.z)+bfbits2f(a.w)
           + bfbits2f(b.x)+bfbits2f(b.y)+bfbits2f(b.z)+bfbits2f(b.w);
    }
    #pragma unroll
    for (int off = 32; off > 0; off >>= 1) s += __shfl_down(s, off, 64);
    if (lane == 0) lbuf[row] = s;
}

// ---- K3: ctx = P@v / l; g = u*ctx written in-place over u ----
__global__ __launch_bounds__(256) void pv_mfma(
    const unsigned short* __restrict__ P, const unsigned short* __restrict__ vT,
    const float* __restrict__ lbuf, unsigned short* __restrict__ u)
{
    __shared__ __align__(16) unsigned short smem[128*CS];
    unsigned short* As = smem;
    unsigned short* Bs = smem + 8192;
    const int tid = threadIdx.x;
    const int z = blockIdx.z;
    const int row0 = blockIdx.y*128, col0 = blockIdx.x*128;
    f32x4 acc[4][4];
    #pragma unroll
    for (int i = 0; i < 4; i++)
        #pragma unroll
        for (int j = 0; j < 4; j++)
            acc[i][j] = (f32x4){0.f,0.f,0.f,0.f};
    mfma_core(P + ((size_t)z*SEQ + row0)*SEQ, SEQ, vT + ((size_t)z*INTER + col0)*SEQ, SEQ,
              As, Bs, acc, tid, SEQ);
    EPILOG_IDX
    __syncthreads();
    #pragma unroll
    for (int j = 0; j < 4; j++) {
        int nl = wn + j*16 + cn;
        #pragma unroll
        for (int i = 0; i < 4; i++) {
            #pragma unroll
            for (int r = 0; r < 4; r++) {
                int rowl = wm + i*16 + r4 + r;
                smem[rowl*CS + nl] = f2bfbits(acc[i][j][r]);
            }
        }
    }
    __syncthreads();
    #pragma unroll
    for (int rnd = 0; rnd < 8; rnd++) {
        int row = rnd*16 + (tid>>4);
        int col = (tid&15)*8;
        int m = z*SEQ + row0 + row;
        float linv = 1.0f / lbuf[m];
        u16x8 cx = *(const u16x8*)&smem[row*CS + col];
        size_t idx = (size_t)m*INTER + col0 + col;
        u16x8 uu = *(const u16x8*)&u[idx];
        u16x8 g;
        #pragma unroll
        for (int t = 0; t < 8; t++)
            g[t] = f2bfbits(bfbits2f(uu[t]) * bfbits2f(cx[t]) * linv);
        *(u16x8*)&u[idx] = g;
    }
}

// ---- K4: out = g@Wo + bo (fp32 out, direct stores) ----
__global__ __launch_bounds__(256) void gemm2_mfma(
    const unsigned short* __restrict__ g, const unsigned short* __restrict__ WoT,
    const float* __restrict__ bo, float* __restrict__ out)
{
    __shared__ __align__(16) unsigned short As[8192];
    __shared__ __align__(16) unsigned short Bs[8192];
    const int tid = threadIdx.x;
    const int row0 = blockIdx.y*128, col0 = blockIdx.x*128;
    f32x4 acc[4][4];
    #pragma unroll
    for (int i = 0; i < 4; i++)
        #pragma unroll
        for (int j = 0; j < 4; j++)
            acc[i][j] = (f32x4){0.f,0.f,0.f,0.f};
    mfma_core(g + (size_t)row0*INTER, INTER, WoT + (size_t)col0*INTER, INTER,
              As, Bs, acc, tid, INTER);
    EPILOG_IDX
    #pragma unroll
    for (int j = 0; j < 4; j++) {
        int n = col0 + wn + j*16 + cn;
        float bon = bo[n];
        #pragma unroll
        for (int i = 0; i < 4; i++) {
            #pragma unroll
            for (int r = 0; r < 4; r++) {
                int m = row0 + wm + i*16 + r4 + r;
                out[(size_t)m*HIDDEN + n] = acc[i][j][r] + bon;
            }
        }
    }
}

extern "C" void kernel_launch(void* const* d_in, const int* in_sizes, int n_in,
                              void* d_out, int out_size, void* d_ws, size_t ws_size,
                              hipStream_t stream)
{
    const float* X     = (const float*)d_in[0];
    const int*   mask  = (const int*)d_in[1];
    const float* Wi    = (const float*)d_in[3];
    const float* bi    = (const float*)d_in[4];
    const float* gamma = (const float*)d_in[5];
    const float* beta  = (const float*)d_in[6];
    const float* Wo    = (const float*)d_in[7];
    const float* bo    = (const float*)d_in[8];
    float* out = (float*)d_out;

    unsigned short* Xb  = (unsigned short*)d_ws;            // 8192*768
    unsigned short* WiT = Xb  + (size_t)MTOT*HIDDEN;        // 3200*768
    unsigned short* WoT = WiT + (size_t)ETOT*HIDDEN;        // 768*1536
    unsigned short* u   = WoT + (size_t)HIDDEN*INTER;       // 8192*1536
    unsigned short* vT  = u   + (size_t)MTOT*INTER;         // 4*1536*2048
    unsigned short* qb  = vT  + (size_t)MTOT*INTER;         // 8192*128
    unsigned short* kb  = qb  + (size_t)MTOT*KEY;           // 8192*128
    unsigned short* P   = kb  + (size_t)MTOT*KEY;           // 4*2048*2048
    float* lb  = (float*)(P + (size_t)NB*SEQ*SEQ);          // 8192
    float* scb = lb + MTOT;                                 // 4

    scale_kernel<<<NB, 256, 0, stream>>>(mask, scb);
    cvt_bf16_kernel<<<(MTOT*HIDDEN/4 + 255)/256, 256, 0, stream>>>(X, Xb, MTOT*HIDDEN/4);
    transpose_cvt<<<dim3(ETOT/32, HIDDEN/32), 256, 0, stream>>>(Wi, WiT, HIDDEN, ETOT);
    transpose_cvt<<<dim3(HIDDEN/32, INTER/32), 256, 0, stream>>>(Wo, WoT, INTER, HIDDEN);
    gemm1_mfma<<<dim3(ETOT/128, MTOT/128), 256, 0, stream>>>(Xb, WiT, bi, gamma, beta, u, vT, qb, kb);
    attn_mfma<<<dim3(SEQ/128, SEQ/128, NB), 256, 0, stream>>>(qb, kb, mask, scb, P);
    rowsum_kernel<<<MTOT/4, 256, 0, stream>>>(P, lb);
    pv_mfma<<<dim3(INTER/128, SEQ/128, NB), 256, 0, stream>>>(P, vT, lb, u);
    gemm2_mfma<<<dim3(HIDDEN/128, MTOT/128), 256, 0, stream>>>(u, WoT, bo, out);
}